// Round 3
// baseline (15.799 us; speedup 1.0000x reference)
//
#include <hip/hip_runtime.h>
#include <hip/hip_bf16.h>

// out[b,y,:] = sum_{a=0}^{y>>3} (k[b,y,:]·q[b,8a,:]) * v[b,8a,:]
// T=2048, anchors=256 (stride 8), E=64, fp32 in/out.
// Two kernels: prep (fp32->bf16 into ws: Kb[b][y][e], Qa[b][a][e], Vt[b][e][a])
// then main (per 32-row tile: S=K·Qa^T masked, out += S·Va via MFMA).

constexpr int T_LEN = 2048;
constexpr int EDIM  = 64;
constexpr int NA    = 256;            // anchors (stride 8)
constexpr int ROWS  = 32;             // rows per tile
constexpr int NTILE = T_LEN / ROWS;   // 64 tiles per batch
constexpr int TE    = T_LEN * EDIM;
constexpr int AE    = NA * EDIM;      // 16384

typedef __attribute__((ext_vector_type(4))) float f32x4;
typedef __attribute__((ext_vector_type(8))) short bf16x8;
typedef __attribute__((ext_vector_type(4))) short bf16x4;

__device__ __forceinline__ short f2bf(float f) {
    __hip_bfloat16 h = __float2bfloat16(f);
    return __builtin_bit_cast(short, h);
}

// ---------------- prep: fp32 -> bf16 with layout changes ----------------
// ws shorts: Qa[B][NA][EDIM] @0 ; Vt[B][EDIM][NA] @B*AE ; Kb[B][T][EDIM] @2*B*AE
__global__ __launch_bounds__(256)
void sh2_prep(const float* __restrict__ kk, const float* __restrict__ qq,
              const float* __restrict__ vv, short* __restrict__ ws, int B)
{
    const int nK = B * TE / 4;    // 262144 for B=8
    const int nQ = B * AE / 4;    // 32768
    short* Qa = ws;
    short* Vt = ws + (size_t)B * AE;
    short* Kb = ws + (size_t)2 * B * AE;

    int tid = blockIdx.x * 256 + threadIdx.x;
    if (tid < nK) {
        f32x4 x = *(const f32x4*)(kk + (size_t)tid * 4);
        bf16x4 r;
        #pragma unroll
        for (int i = 0; i < 4; ++i) r[i] = f2bf(x[i]);
        *(bf16x4*)(Kb + (size_t)tid * 4) = r;
    } else if (tid < nK + nQ) {
        int t = tid - nK;                    // [B][NA][EDIM/4]
        int e4 = t & 15, a = (t >> 4) & 255, b = t >> 12;
        f32x4 x = *(const f32x4*)(qq + ((size_t)b * T_LEN + 8 * a) * EDIM + e4 * 4);
        bf16x4 r;
        #pragma unroll
        for (int i = 0; i < 4; ++i) r[i] = f2bf(x[i]);
        *(bf16x4*)(Qa + (size_t)t * 4) = r;
    } else if (tid < nK + 2 * nQ) {
        int t = tid - nK - nQ;               // [B][EDIM][NA/4]
        int a4 = t & 63, e = (t >> 6) & 63, b = t >> 12;
        bf16x4 r;
        #pragma unroll
        for (int i = 0; i < 4; ++i)
            r[i] = f2bf(vv[((size_t)b * T_LEN + 8 * (a4 * 4 + i)) * EDIM + e]);
        *(bf16x4*)(Vt + (size_t)t * 4) = r;
    }
}

// ---------------- main ----------------
constexpr int EP = 76;   // pbuf padded stride (16B-aligned, spreads g-groups)

__global__ __launch_bounds__(256, 2)
void sh2_main(const short* __restrict__ ws, float* __restrict__ out, int B)
{
    __shared__ alignas(16) short slds[4][ROWS * 32];   // per-wave S scratch, 8 KB
    __shared__ float pbuf[4][ROWS][EP];                // cross-wave partials, 38 KB

    const int bid = blockIdx.x;
    const int p   = NTILE - 1 - (bid >> 3);   // big tiles dispatch first
    const int b   = bid & 7;
    const int w    = threadIdx.x >> 6;
    const int lane = threadIdx.x & 63;
    const int g = lane >> 4, ln = lane & 15;

    const short* Qa = ws + (size_t)b * AE;
    const short* Vt = ws + (size_t)B * AE + (size_t)b * AE;
    const short* Kb = ws + (size_t)2 * B * AE + (size_t)b * TE;

    const int y0  = ROWS * p;
    const int nat = (((4 * p + 3) >> 5)) + 1;   // anchor-tiles for this tile (1..8)

    // K A-frags, resident: Kf[mt][eh], m=ln, k = eh*32 + 8g + i
    bf16x8 Kf[2][2];
    #pragma unroll
    for (int mt = 0; mt < 2; ++mt)
        #pragma unroll
        for (int eh = 0; eh < 2; ++eh)
            Kf[mt][eh] = *(const bf16x8*)(Kb + (size_t)(y0 + mt * 16 + ln) * EDIM + eh * 32 + g * 8);

    const f32x4 vzero = {0.f, 0.f, 0.f, 0.f};
    f32x4 acc[2][4];
    #pragma unroll
    for (int i = 0; i < 2; ++i)
        #pragma unroll
        for (int j = 0; j < 4; ++j) acc[i][j] = vzero;

    short* sl = slds[w];

    for (int ai = w; ai < nat; ai += 4) {
        const int a0 = ai * 32;

        // Q B-frags direct from bf16: n = a0+nt*16+ln, k = eh*32+8g+i
        bf16x8 Qf[2][2];
        #pragma unroll
        for (int nt = 0; nt < 2; ++nt)
            #pragma unroll
            for (int eh = 0; eh < 2; ++eh)
                Qf[nt][eh] = *(const bf16x8*)(Qa + (size_t)(a0 + nt * 16 + ln) * EDIM + eh * 32 + g * 8);

        // V B-frags direct from transposed bf16: n = et*16+ln (e), k = a0+8g+i
        bf16x8 Vf[4];
        #pragma unroll
        for (int et = 0; et < 4; ++et)
            Vf[et] = *(const bf16x8*)(Vt + (size_t)(et * 16 + ln) * NA + a0 + g * 8);

        // stage 1: S = K · Qa^T
        f32x4 S[2][2];
        #pragma unroll
        for (int mt = 0; mt < 2; ++mt)
            #pragma unroll
            for (int nt = 0; nt < 2; ++nt) {
                f32x4 s = vzero;
                s = __builtin_amdgcn_mfma_f32_16x16x32_bf16(Kf[mt][0], Qf[nt][0], s, 0, 0, 0);
                s = __builtin_amdgcn_mfma_f32_16x16x32_bf16(Kf[mt][1], Qf[nt][1], s, 0, 0, 0);
                S[mt][nt] = s;
            }

        // mask partial anchors (only the last anchor-tile)
        if (ai == nat - 1) {
            #pragma unroll
            for (int mt = 0; mt < 2; ++mt)
                #pragma unroll
                for (int nt = 0; nt < 2; ++nt)
                    #pragma unroll
                    for (int r = 0; r < 4; ++r) {
                        int y = y0 + mt * 16 + g * 4 + r;
                        int a = a0 + nt * 16 + ln;
                        if (8 * a > y) S[mt][nt][r] = 0.f;
                    }
        }

        // S -> LDS bf16, swizzle f(row)=(row>>2)&3 spreads g-groups across banks
        #pragma unroll
        for (int mt = 0; mt < 2; ++mt)
            #pragma unroll
            for (int nt = 0; nt < 2; ++nt)
                #pragma unroll
                for (int r = 0; r < 4; ++r) {
                    int row = mt * 16 + g * 4 + r;
                    int a   = nt * 16 + ln;
                    sl[row * 32 + ((((a >> 3) ^ ((row >> 2) & 3))) << 3) + (a & 7)] = f2bf(S[mt][nt][r]);
                }

        // read back as stage-2 A-frags: m = ln, k = 8g+i
        bf16x8 SA[2];
        #pragma unroll
        for (int mt = 0; mt < 2; ++mt) {
            int row = mt * 16 + ln;
            SA[mt] = *(const bf16x8*)(sl + row * 32 + ((g ^ ((row >> 2) & 3)) << 3));
        }

        // stage 2: acc += S · Va
        #pragma unroll
        for (int et = 0; et < 4; ++et)
            #pragma unroll
            for (int mt = 0; mt < 2; ++mt)
                acc[mt][et] = __builtin_amdgcn_mfma_f32_16x16x32_bf16(SA[mt], Vf[et], acc[mt][et], 0, 0, 0);
    }

    // cross-wave reduction via LDS
    #pragma unroll
    for (int mt = 0; mt < 2; ++mt)
        #pragma unroll
        for (int et = 0; et < 4; ++et)
            #pragma unroll
            for (int r = 0; r < 4; ++r)
                pbuf[w][mt * 16 + g * 4 + r][et * 16 + ln] = acc[mt][et][r];

    __syncthreads();

    const int row = w * 8 + (lane >> 3);
    const int e0  = (lane & 7) * 8;
    f32x4 s0 = vzero, s1 = vzero;
    #pragma unroll
    for (int w2 = 0; w2 < 4; ++w2) {
        s0 += *(const f32x4*)&pbuf[w2][row][e0];
        s1 += *(const f32x4*)&pbuf[w2][row][e0 + 4];
    }
    float* o = out + ((size_t)b * T_LEN + y0 + row) * EDIM + e0;
    *(f32x4*)o       = s0;
    *(f32x4*)(o + 4) = s1;
}

extern "C" void kernel_launch(void* const* d_in, const int* in_sizes, int n_in,
                              void* d_out, int out_size, void* d_ws, size_t ws_size,
                              hipStream_t stream) {
    const float* kk = (const float*)d_in[0];
    const float* qq = (const float*)d_in[1];
    const float* vv = (const float*)d_in[2];
    float* o        = (float*)d_out;
    short* ws       = (short*)d_ws;
    int B = in_sizes[0] / TE;

    int prep_units = B * TE / 4 + 2 * (B * AE / 4);   // 327680 for B=8
    int prep_grid  = (prep_units + 255) / 256;        // 1280
    sh2_prep<<<prep_grid, 256, 0, stream>>>(kk, qq, vv, ws, B);
    sh2_main<<<B * NTILE, 256, 0, stream>>>(ws, o, B);
}